// Round 1
// baseline (138.411 us; speedup 1.0000x reference)
//
#include <hip/hip_runtime.h>
#include <math.h>

// Problem constants (from reference setup_inputs)
constexpr int B = 16, N = 1024, Cin = 64, C = 64, K = 3;
#define LN_EPS 1e-5f

// ---------------------------------------------------------------------------
// Kernel 1: Xs[b,n] = sum_c X[b,n,c]   (Cin == 64 == wave width)
// one wave per (b,n); lane = c; coalesced load + butterfly reduce
// ---------------------------------------------------------------------------
__global__ void __launch_bounds__(256) k_sumx(const float* __restrict__ X,
                                              float* __restrict__ P0) {
    int wave = (blockIdx.x * blockDim.x + threadIdx.x) >> 6;  // b*N + n
    int lane = threadIdx.x & 63;
    float v = X[(size_t)wave * Cin + lane];
    #pragma unroll
    for (int off = 32; off; off >>= 1) v += __shfl_xor(v, off);
    if (lane == 0) P0[wave] = v;
}

// ---------------------------------------------------------------------------
// Kernel 2: ht[i][n][c] = h[i][c][n]  (transpose so epilogue reads coalesced)
// 64x64 LDS tile with +1 pad; grid = (K+1) * (N/64) blocks of 256
// ---------------------------------------------------------------------------
__global__ void __launch_bounds__(256) k_transpose_h(const float* __restrict__ h,
                                                     float* __restrict__ ht) {
    __shared__ float tile[64][65];
    int i  = blockIdx.x / (N / 64);
    int n0 = (blockIdx.x % (N / 64)) * 64;
    int tx = threadIdx.x & 63;   // n-offset on read, c on write
    int ty = threadIdx.x >> 6;   // 0..3
    const float* hi = h + (size_t)i * C * N;
    #pragma unroll
    for (int cc = ty; cc < 64; cc += 4)
        tile[cc][tx] = hi[(size_t)cc * N + n0 + tx];   // coalesced along n
    __syncthreads();
    float* hti = ht + (size_t)i * N * C;
    #pragma unroll
    for (int nn = ty; nn < 64; nn += 4)
        hti[(size_t)(n0 + nn) * C + tx] = tile[tx][nn]; // coalesced along c
}

// ---------------------------------------------------------------------------
// Kernel 3: y[b,row] = dot(A[b,row,:], x[b,:])  batched matvec
// block = 256 (4 waves); block handles 16 rows of one batch (4 rows/wave,
// sharing the LDS x reads across the 4 rows). float4 everywhere.
// grid = B * N/16 = 1024 blocks
// ---------------------------------------------------------------------------
__global__ void __launch_bounds__(256) k_matvec(const float* __restrict__ A,
                                                const float* __restrict__ x,
                                                float* __restrict__ y) {
    __shared__ float4 xs[N / 4];                      // 4 KB: x[b,:]
    int b    = blockIdx.x >> 6;                       // 64 blocks per batch
    int row0 = (blockIdx.x & 63) << 4;                // 16 rows per block
    const float4* xv = (const float4*)(x + (size_t)b * N);
    xs[threadIdx.x] = xv[threadIdx.x];
    __syncthreads();

    int w    = threadIdx.x >> 6;
    int lane = threadIdx.x & 63;
    int row  = row0 + w * 4;                          // this wave: rows row..row+3
    const float* Ab = A + ((size_t)b << 20);          // b * N*N
    const float4* r0 = (const float4*)(Ab + (size_t)(row + 0) * N);
    const float4* r1 = (const float4*)(Ab + (size_t)(row + 1) * N);
    const float4* r2 = (const float4*)(Ab + (size_t)(row + 2) * N);
    const float4* r3 = (const float4*)(Ab + (size_t)(row + 3) * N);

    float a0 = 0.f, a1 = 0.f, a2 = 0.f, a3 = 0.f;
    #pragma unroll
    for (int k = 0; k < 4; ++k) {
        int idx = k * 64 + lane;
        float4 xx = xs[idx];
        float4 v0 = r0[idx];
        float4 v1 = r1[idx];
        float4 v2 = r2[idx];
        float4 v3 = r3[idx];
        a0 += v0.x * xx.x + v0.y * xx.y + v0.z * xx.z + v0.w * xx.w;
        a1 += v1.x * xx.x + v1.y * xx.y + v1.z * xx.z + v1.w * xx.w;
        a2 += v2.x * xx.x + v2.y * xx.y + v2.z * xx.z + v2.w * xx.w;
        a3 += v3.x * xx.x + v3.y * xx.y + v3.z * xx.z + v3.w * xx.w;
    }
    #pragma unroll
    for (int off = 32; off; off >>= 1) {
        a0 += __shfl_xor(a0, off);
        a1 += __shfl_xor(a1, off);
        a2 += __shfl_xor(a2, off);
        a3 += __shfl_xor(a3, off);
    }
    if (lane == 0) {
        float* yb = y + (size_t)b * N + row;
        yb[0] = a0; yb[1] = a1; yb[2] = a2; yb[3] = a3;
    }
}

// ---------------------------------------------------------------------------
// Kernel 4: Y[b,n,c] = sum_i ht[i,n,c] * P[i,b,n]; LayerNorm over c; tanh.
// one wave per (b,n); lane = c (C == 64 == wave width)
// ---------------------------------------------------------------------------
__global__ void __launch_bounds__(256) k_epilogue(const float* __restrict__ P,
                                                  const float* __restrict__ ht,
                                                  const float* __restrict__ gamma,
                                                  const float* __restrict__ beta,
                                                  float* __restrict__ out) {
    int wave = (blockIdx.x * blockDim.x + threadIdx.x) >> 6;  // b*N + n
    int lane = threadIdx.x & 63;                               // c
    int b = wave >> 10;        // N = 1024
    int n = wave & 1023;

    float y = 0.f;
    #pragma unroll
    for (int i = 0; i <= K; ++i) {
        float hv = ht[((size_t)i * N + n) * C + lane];   // coalesced
        float pv = P[((size_t)i * B + b) * N + n];       // wave-broadcast
        y += hv * pv;
    }
    // mean over 64 channels
    float s = y;
    #pragma unroll
    for (int off = 32; off; off >>= 1) s += __shfl_xor(s, off);
    float mu = s * (1.0f / 64.0f);
    float d = y - mu;
    // population variance over 64 channels
    float v = d * d;
    #pragma unroll
    for (int off = 32; off; off >>= 1) v += __shfl_xor(v, off);
    float var = v * (1.0f / 64.0f);
    float yn = d * rsqrtf(var + LN_EPS) * gamma[lane] + beta[lane];
    out[(size_t)wave * C + lane] = tanhf(yn);
}

// ---------------------------------------------------------------------------
extern "C" void kernel_launch(void* const* d_in, const int* in_sizes, int n_in,
                              void* d_out, int out_size, void* d_ws, size_t ws_size,
                              hipStream_t stream) {
    const float* A     = (const float*)d_in[0];  // [B,N,N]
    const float* X     = (const float*)d_in[1];  // [B,N,Cin]
    const float* h     = (const float*)d_in[2];  // [K+1,C,N]
    const float* gamma = (const float*)d_in[3];  // [C]
    const float* beta  = (const float*)d_in[4];  // [C]
    float* out = (float*)d_out;                  // [B,N,C]

    // workspace layout (f32): P[(K+1)][B][N] then ht[(K+1)][N][C]
    float* P  = (float*)d_ws;
    float* ht = P + (size_t)(K + 1) * B * N;

    // 1. P[0] = X.sum(-1)
    k_sumx<<<B * N / 4, 256, 0, stream>>>(X, P);
    // 2. ht = transpose(h) for coalesced epilogue reads
    k_transpose_h<<<(K + 1) * (N / 64), 256, 0, stream>>>(h, ht);
    // 3. P[i+1] = A @ P[i]  (serially dependent; A should stay L3-resident)
    for (int i = 0; i < K; ++i)
        k_matvec<<<B * (N / 16), 256, 0, stream>>>(A, P + (size_t)i * B * N,
                                                   P + (size_t)(i + 1) * B * N);
    // 4. taps + LayerNorm + tanh
    k_epilogue<<<B * N / 4, 256, 0, stream>>>(P, ht, gamma, beta, out);
}

// Round 4
// 136.597 us; speedup vs baseline: 1.0133x; 1.0133x over previous
//
#include <hip/hip_runtime.h>
#include <math.h>

// Problem constants (from reference setup_inputs)
constexpr int B = 16, N = 1024, Cin = 64, C = 64, K = 3;
#define LN_EPS 1e-5f

// ---------------------------------------------------------------------------
// Kernel 0: (a) P0[b*N+n] = sum_c X[b,n,c]   (wave per (b,n), lane = c)
//           (b) ht[i][n][c] = h[i][c][n]     (blocks 0..63, 64x64 LDS tile)
// grid = 1024 blocks x 256
// ---------------------------------------------------------------------------
__global__ void __launch_bounds__(256) k_front(const float* __restrict__ X,
                                               const float* __restrict__ h,
                                               float* __restrict__ P,
                                               float* __restrict__ ht) {
    __shared__ float tile[64 * 65];
    const int tid  = threadIdx.x;
    const int lane = tid & 63;
    const int w    = tid >> 6;
    const int gw   = blockIdx.x * 4 + w;            // 0..4095

    // (a) Xs: 4 strided iterations cover B*N = 16384 waves of work
    for (int p = gw; p < B * N; p += 4096) {
        float v = X[(size_t)p * Cin + lane];
        #pragma unroll
        for (int off = 32; off; off >>= 1) v += __shfl_xor(v, off);
        if (lane == 0) P[p] = v;
    }

    // (b) transpose h: 64 blocks, one 64x64 tile each
    if (blockIdx.x < (K + 1) * (N / 64)) {
        int i  = blockIdx.x / (N / 64);
        int n0 = (blockIdx.x % (N / 64)) * 64;
        const float* hi = h + (size_t)i * C * N;
        #pragma unroll
        for (int cc = w; cc < 64; cc += 4)
            tile[cc * 65 + lane] = hi[(size_t)cc * N + n0 + lane];   // coalesced along n
        __syncthreads();
        float* hti = ht + (size_t)i * N * C;
        #pragma unroll
        for (int nn = w; nn < 64; nn += 4)
            hti[(size_t)(n0 + nn) * C + lane] = tile[lane * 65 + nn]; // coalesced along c
    }
}

// ---------------------------------------------------------------------------
// Matvec core: wave computes rows row..row+3 of A[b] @ x (x staged in LDS).
// Returns the 4 dots in a0..a3 (valid in lane 0 only).
// ---------------------------------------------------------------------------
__device__ __forceinline__ void matvec4(const float* __restrict__ Ab,
                                        const float4* __restrict__ xs,
                                        int row, int lane,
                                        float& a0, float& a1, float& a2, float& a3) {
    const float4* r0 = (const float4*)(Ab + (size_t)(row + 0) * N);
    const float4* r1 = (const float4*)(Ab + (size_t)(row + 1) * N);
    const float4* r2 = (const float4*)(Ab + (size_t)(row + 2) * N);
    const float4* r3 = (const float4*)(Ab + (size_t)(row + 3) * N);
    a0 = a1 = a2 = a3 = 0.f;
    #pragma unroll
    for (int k = 0; k < 4; ++k) {
        int idx = k * 64 + lane;
        float4 xx = xs[idx];
        float4 v0 = r0[idx];
        float4 v1 = r1[idx];
        float4 v2 = r2[idx];
        float4 v3 = r3[idx];
        a0 += v0.x * xx.x + v0.y * xx.y + v0.z * xx.z + v0.w * xx.w;
        a1 += v1.x * xx.x + v1.y * xx.y + v1.z * xx.z + v1.w * xx.w;
        a2 += v2.x * xx.x + v2.y * xx.y + v2.z * xx.z + v2.w * xx.w;
        a3 += v3.x * xx.x + v3.y * xx.y + v3.z * xx.z + v3.w * xx.w;
    }
    #pragma unroll
    for (int off = 32; off; off >>= 1) {
        a0 += __shfl_xor(a0, off);
        a1 += __shfl_xor(a1, off);
        a2 += __shfl_xor(a2, off);
        a3 += __shfl_xor(a3, off);
    }
}

// ---------------------------------------------------------------------------
// Kernel 1: y[b,row] = dot(A[b,row,:], x[b,:])   (passes 1 and 2)
// grid = B * N/16 = 1024 blocks x 256; block = 16 rows of one batch
// ---------------------------------------------------------------------------
__global__ void __launch_bounds__(256) k_matvec(const float* __restrict__ A,
                                                const float* __restrict__ x,
                                                float* __restrict__ y) {
    __shared__ __align__(16) float4 xs[N / 4];      // 4 KB: x[b,:]
    const int b    = blockIdx.x >> 6;
    const int row0 = (blockIdx.x & 63) << 4;
    xs[threadIdx.x] = ((const float4*)(x + (size_t)b * N))[threadIdx.x];
    __syncthreads();

    const int w    = threadIdx.x >> 6;
    const int lane = threadIdx.x & 63;
    float a0, a1, a2, a3;
    matvec4(A + ((size_t)b << 20), xs, row0 + w * 4, lane, a0, a1, a2, a3);
    if (lane == 0) {
        float* yb = y + (size_t)b * N + row0 + w * 4;
        yb[0] = a0; yb[1] = a1; yb[2] = a2; yb[3] = a3;
    }
}

// ---------------------------------------------------------------------------
// Kernel 2: pass 3 matvec fused with taps + LayerNorm + tanh.
// Block computes P3 for 16 (b,n) pairs, keeps them in LDS, then each wave
// handles 4 n-values with lane = c.
// ---------------------------------------------------------------------------
__global__ void __launch_bounds__(256) k_last(const float* __restrict__ A,
                                              const float* __restrict__ P,   // [3][B][N]
                                              const float* __restrict__ ht,  // [K+1][N][C]
                                              const float* __restrict__ gamma,
                                              const float* __restrict__ beta,
                                              float* __restrict__ out) {
    __shared__ __align__(16) float4 xs[N / 4];      // x = P2[b,:]
    __shared__ float p3s[16];
    const int b    = blockIdx.x >> 6;
    const int row0 = (blockIdx.x & 63) << 4;
    const float* x2 = P + (size_t)2 * B * N + (size_t)b * N;
    xs[threadIdx.x] = ((const float4*)x2)[threadIdx.x];
    __syncthreads();

    const int w    = threadIdx.x >> 6;
    const int lane = threadIdx.x & 63;
    float a0, a1, a2, a3;
    matvec4(A + ((size_t)b << 20), xs, row0 + w * 4, lane, a0, a1, a2, a3);
    if (lane == 0) {
        p3s[w * 4 + 0] = a0; p3s[w * 4 + 1] = a1;
        p3s[w * 4 + 2] = a2; p3s[w * 4 + 3] = a3;
    }
    __syncthreads();

    // epilogue: wave w handles n = row0 + w*4 + j, lane = c
    const float g = gamma[lane];
    const float be = beta[lane];
    #pragma unroll
    for (int j = 0; j < 4; ++j) {
        const int nn = w * 4 + j;
        const int n  = row0 + nn;
        float y = 0.f;
        #pragma unroll
        for (int i = 0; i < 3; ++i) {
            float hv = ht[((size_t)i * N + n) * C + lane];          // coalesced
            float pv = P[(size_t)i * B * N + (size_t)b * N + n];    // broadcast
            y += hv * pv;
        }
        y += ht[((size_t)3 * N + n) * C + lane] * p3s[nn];
        float s = y;
        #pragma unroll
        for (int off = 32; off; off >>= 1) s += __shfl_xor(s, off);
        float mu = s * (1.0f / 64.0f);
        float d  = y - mu;
        float v  = d * d;
        #pragma unroll
        for (int off = 32; off; off >>= 1) v += __shfl_xor(v, off);
        float var = v * (1.0f / 64.0f);
        float yn  = d * rsqrtf(var + LN_EPS) * g + be;
        out[((size_t)b * N + n) * C + lane] = tanhf(yn);
    }
}

// ---------------------------------------------------------------------------
extern "C" void kernel_launch(void* const* d_in, const int* in_sizes, int n_in,
                              void* d_out, int out_size, void* d_ws, size_t ws_size,
                              hipStream_t stream) {
    const float* A     = (const float*)d_in[0];  // [B,N,N]
    const float* X     = (const float*)d_in[1];  // [B,N,Cin]
    const float* h     = (const float*)d_in[2];  // [K+1,C,N]
    const float* gamma = (const float*)d_in[3];  // [C]
    const float* beta  = (const float*)d_in[4];  // [C]
    float* out = (float*)d_out;                  // [B,N,C]

    // workspace: P[3][B][N] (192 KB) then ht[(K+1)][N][C] (1 MB)
    float* P  = (float*)d_ws;
    float* ht = P + (size_t)3 * B * N;

    k_front<<<1024, 256, 0, stream>>>(X, h, P, ht);                 // P0, ht
    k_matvec<<<B * (N / 16), 256, 0, stream>>>(A, P, P + (size_t)B * N);          // P1
    k_matvec<<<B * (N / 16), 256, 0, stream>>>(A, P + (size_t)B * N,
                                               P + (size_t)2 * B * N);            // P2
    k_last<<<B * (N / 16), 256, 0, stream>>>(A, P, ht, gamma, beta, out);         // P3+LN+tanh
}